// Round 2
// baseline (898.427 us; speedup 1.0000x reference)
//
#include <hip/hip_runtime.h>

constexpr int   FEAT  = 128;
constexpr int   BATCH = 512;
constexpr int   NNEG  = 4096;            // 2^12
constexpr int   NREF  = BATCH * NNEG;    // 2,097,152
constexpr long  NDATA = 1200000;
constexpr float INV_TEMP = 14.285714285714286f;  // 1/0.07
constexpr float LOG2E    = 1.4426950408889634f;
constexpr float LN2      = 0.6931471805599453f;
constexpr float K1       = INV_TEMP * LOG2E;

constexpr int SCAN_CHUNK = 1024;
constexpr int NSCAN_BLK  = (int)((NDATA + SCAN_CHUNK - 1) / SCAN_CHUNK); // 1172

// ---------------- zero the histogram bins ----------------------------------
__global__ __launch_bounds__(256) void zero_kernel(int* __restrict__ p, int n) {
  int i = blockIdx.x * blockDim.x + threadIdx.x;
  const int stride = gridDim.x * blockDim.x;
  for (; i < n; i += stride) p[i] = 0;
}

// ---------------- prep: normalize s,t and compute pos logit ----------------
__global__ __launch_bounds__(128) void prep_kernel(
    const float* __restrict__ sf, const float* __restrict__ tf,
    float* __restrict__ s_n, float* __restrict__ t_n, float* __restrict__ pos) {
  const int b = blockIdx.x, t = threadIdx.x;
  const float sv = sf[b * FEAT + t];
  const float tv = tf[b * FEAT + t];
  float ss = sv * sv, tt = tv * tv, st = sv * tv;
#pragma unroll
  for (int m = 1; m < 64; m <<= 1) {
    ss += __shfl_xor(ss, m);
    tt += __shfl_xor(tt, m);
    st += __shfl_xor(st, m);
  }
  __shared__ float sh[6];
  if ((t & 63) == 0) {
    const int w = t >> 6;
    sh[w * 3 + 0] = ss; sh[w * 3 + 1] = tt; sh[w * 3 + 2] = st;
  }
  __syncthreads();
  ss = sh[0] + sh[3]; tt = sh[1] + sh[4]; st = sh[2] + sh[5];
  const float snorm = fmaxf(sqrtf(ss), 1e-12f);
  const float tnorm = fmaxf(sqrtf(tt), 1e-12f);
  s_n[b * FEAT + t] = sv / snorm;
  t_n[b * FEAT + t] = tv / tnorm;
  if (t == 0) pos[b] = st / (snorm * tnorm) * INV_TEMP;
}

// ---------------- histogram of neg_indices over bank rows ------------------
__global__ __launch_bounds__(256) void hist_kernel(
    const int* __restrict__ nidx, int* __restrict__ cnt) {
  int i = blockIdx.x * blockDim.x + threadIdx.x;
  const int stride = gridDim.x * blockDim.x;
  for (; i < NREF; i += stride) atomicAdd(&cnt[nidx[i]], 1);
}

// ---------------- 3-pass exclusive scan (in place) -------------------------
__global__ __launch_bounds__(256) void scan1_kernel(
    int* __restrict__ data, int* __restrict__ bsum) {
  __shared__ int sh[256];
  const int t = threadIdx.x;
  const long base = (long)blockIdx.x * SCAN_CHUNK + t * 4;
  int e0 = 0, e1 = 0, e2 = 0, e3 = 0;
  if (base + 0 < NDATA) e0 = data[base + 0];
  if (base + 1 < NDATA) e1 = data[base + 1];
  if (base + 2 < NDATA) e2 = data[base + 2];
  if (base + 3 < NDATA) e3 = data[base + 3];
  const int s = e0 + e1 + e2 + e3;
  sh[t] = s;
  __syncthreads();
  for (int off = 1; off < 256; off <<= 1) {
    int v = (t >= off) ? sh[t - off] : 0;
    __syncthreads();
    sh[t] += v;
    __syncthreads();
  }
  const int excl = sh[t] - s;
  if (base + 0 < NDATA) data[base + 0] = excl;
  if (base + 1 < NDATA) data[base + 1] = excl + e0;
  if (base + 2 < NDATA) data[base + 2] = excl + e0 + e1;
  if (base + 3 < NDATA) data[base + 3] = excl + e0 + e1 + e2;
  if (t == 255) bsum[blockIdx.x] = sh[255];
}

__global__ __launch_bounds__(256) void scan2_kernel(int* __restrict__ bsum) {
  __shared__ int sh[256];
  const int t = threadIdx.x;
  int e[5];
  int s = 0;
#pragma unroll
  for (int i = 0; i < 5; ++i) {
    const int idx = t * 5 + i;
    e[i] = (idx < NSCAN_BLK) ? bsum[idx] : 0;
    s += e[i];
  }
  sh[t] = s;
  __syncthreads();
  for (int off = 1; off < 256; off <<= 1) {
    int v = (t >= off) ? sh[t - off] : 0;
    __syncthreads();
    sh[t] += v;
    __syncthreads();
  }
  int run = sh[t] - s;
#pragma unroll
  for (int i = 0; i < 5; ++i) {
    const int idx = t * 5 + i;
    if (idx < NSCAN_BLK) bsum[idx] = run;
    run += e[i];
  }
}

__global__ __launch_bounds__(256) void scan3_kernel(
    int* __restrict__ data, const int* __restrict__ bsum) {
  const int add = bsum[blockIdx.x];
  const long base = (long)blockIdx.x * SCAN_CHUNK + threadIdx.x * 4;
#pragma unroll
  for (int i = 0; i < 4; ++i)
    if (base + i < NDATA) data[base + i] += add;
}

// ---------------- scatter refs into CSR buckets ----------------------------
__global__ __launch_bounds__(256) void scatter_kernel(
    const int* __restrict__ nidx, int* __restrict__ cursor, int* __restrict__ refs) {
  int i = blockIdx.x * blockDim.x + threadIdx.x;
  const int stride = gridDim.x * blockDim.x;
  for (; i < NREF; i += stride) {
    const int r = nidx[i];
    const int pos = atomicAdd(&cursor[r], 1);
    refs[pos] = i;   // i encodes (b = i>>12, k = i&4095); term slot is unique
  }
}

// -------- fused: stream bank once -> copy out + compute ref dot/exp --------
__global__ __launch_bounds__(256) void fused_kernel(
    const float* __restrict__ src, const int* __restrict__ cursor,
    const int* __restrict__ refs, const float* __restrict__ s_n,
    float* __restrict__ term, float* __restrict__ dst) {
  const int lane = threadIdx.x & 63;
  const int nw = gridDim.x * (blockDim.x >> 6);
  long r = (long)blockIdx.x * (blockDim.x >> 6) + (threadIdx.x >> 6);
  if (r >= NDATA) return;
  float2 v = *(const float2*)(src + r * FEAT + 2 * lane);
  while (r < NDATA) {
    const long rn = r + nw;
    float2 vn = make_float2(0.f, 0.f);
    if (rn < NDATA) vn = *(const float2*)(src + rn * FEAT + 2 * lane);  // prefetch
    // copy out (dst is 4B-aligned only: scalar dword stores)
    dst[r * FEAT + 2 * lane]     = v.x;
    dst[r * FEAT + 2 * lane + 1] = v.y;
    const int end   = cursor[r];                    // inclusive prefix after scatter
    const int start = (r == 0) ? 0 : cursor[r - 1]; // = exclusive prefix of r
    for (int j = start; j < end; ++j) {
      const int e = refs[j];
      const int b = e >> 12;
      const float2 s2 = *(const float2*)(s_n + b * FEAT + 2 * lane);
      float p = fmaf(s2.x, v.x, s2.y * v.y);
#pragma unroll
      for (int m = 1; m < 64; m <<= 1) p += __shfl_xor(p, m);
      if (lane == 0) term[e] = exp2f(fmaf(p, K1, -K1));  // exp(logit - C), <= 1
    }
    v = vn; r = rn;
  }
}

// ---------------- per-row logsumexp ----------------------------------------
__global__ __launch_bounds__(256) void rowloss_kernel(
    const float* __restrict__ term, const float* __restrict__ pos,
    float* __restrict__ rowloss) {
  const int b = blockIdx.x, t = threadIdx.x;
  float acc = 0.f;
  for (int k = t; k < NNEG; k += 256) acc += term[b * NNEG + k];
#pragma unroll
  for (int m = 1; m < 64; m <<= 1) acc += __shfl_xor(acc, m);
  __shared__ float sh[4];
  if ((t & 63) == 0) sh[t >> 6] = acc;
  __syncthreads();
  if (t == 0) {
    float tot = sh[0] + sh[1] + sh[2] + sh[3];
    const float p = pos[b];
    tot += exp2f(fmaf(p, LOG2E, -K1));              // exp(pos - C)
    rowloss[b] = INV_TEMP + log2f(tot) * LN2 - p;   // C + ln(tot) - pos
  }
}

// ---------------- mean over rows -------------------------------------------
__global__ __launch_bounds__(512) void mean_kernel(
    const float* __restrict__ rowloss, float* __restrict__ out) {
  const int t = threadIdx.x;
  float l = rowloss[t];
#pragma unroll
  for (int m = 1; m < 64; m <<= 1) l += __shfl_xor(l, m);
  __shared__ float sh[8];
  if ((t & 63) == 0) sh[t >> 6] = l;
  __syncthreads();
  if (t == 0) {
    float s = 0.f;
#pragma unroll
    for (int i = 0; i < 8; ++i) s += sh[i];
    out[0] = s / (float)BATCH;
  }
}

// ------------- EMA scatter update with last-writer-wins --------------------
__global__ __launch_bounds__(128) void update_kernel(
    const float* __restrict__ neg, const float* __restrict__ t_n,
    const int* __restrict__ indices, float* __restrict__ dst) {
  const int b = blockIdx.x, t = threadIdx.x;
  __shared__ int sidx[BATCH];
  __shared__ int flag;
  if (t == 0) flag = 0;
  for (int j = t; j < BATCH; j += 128) sidx[j] = indices[j];
  __syncthreads();
  const int idx = sidx[b];
  int later = 0;
  for (int j = t; j < BATCH; j += 128)
    if (j > b && sidx[j] == idx) later = 1;
  if (later) flag = 1;  // benign same-value race
  __syncthreads();
  if (flag) return;     // a later batch element writes this row (last wins)
  const float u = 0.5f * neg[(long)idx * FEAT + t] + 0.5f * t_n[b * FEAT + t];
  float uu = u * u;
#pragma unroll
  for (int m = 1; m < 64; m <<= 1) uu += __shfl_xor(uu, m);
  __shared__ float sh2[2];
  if ((t & 63) == 0) sh2[t >> 6] = uu;
  __syncthreads();
  const float nrm = fmaxf(sqrtf(sh2[0] + sh2[1]), 1e-12f);
  dst[(long)idx * FEAT + t] = u / nrm;
}

extern "C" void kernel_launch(void* const* d_in, const int* in_sizes, int n_in,
                              void* d_out, int out_size, void* d_ws, size_t ws_size,
                              hipStream_t stream) {
  const float* student   = (const float*)d_in[0];
  const float* teacher   = (const float*)d_in[1];
  const float* negatives = (const float*)d_in[2];
  const int*   indices   = (const int*)d_in[3];
  const int*   neg_idx   = (const int*)d_in[4];
  float* out = (float*)d_out;

  // workspace layout (~22.1 MB)
  int*   cursor  = (int*)d_ws;                 // NDATA
  int*   bsum    = cursor + NDATA;             // NSCAN_BLK (padded to 2048)
  int*   refs    = bsum + 2048;                // NREF
  float* term    = (float*)(refs + NREF);      // NREF
  float* s_n     = term + NREF;                // BATCH*FEAT
  float* t_n     = s_n + BATCH * FEAT;         // BATCH*FEAT
  float* pos     = t_n + BATCH * FEAT;         // BATCH
  float* rowloss = pos + BATCH;                // BATCH

  zero_kernel<<<1024, 256, 0, stream>>>(cursor, (int)NDATA);
  prep_kernel<<<BATCH, 128, 0, stream>>>(student, teacher, s_n, t_n, pos);
  hist_kernel<<<2048, 256, 0, stream>>>(neg_idx, cursor);
  scan1_kernel<<<NSCAN_BLK, 256, 0, stream>>>(cursor, bsum);
  scan2_kernel<<<1, 256, 0, stream>>>(bsum);
  scan3_kernel<<<NSCAN_BLK, 256, 0, stream>>>(cursor, bsum);
  scatter_kernel<<<2048, 256, 0, stream>>>(neg_idx, cursor, refs);
  fused_kernel<<<2048, 256, 0, stream>>>(negatives, cursor, refs, s_n, term, out + 1);
  rowloss_kernel<<<BATCH, 256, 0, stream>>>(term, pos, rowloss);
  mean_kernel<<<1, 512, 0, stream>>>(rowloss, out);
  update_kernel<<<BATCH, 128, 0, stream>>>(negatives, t_n, indices, out + 1);
}

// Round 4
// 402.132 us; speedup vs baseline: 2.2342x; 2.2342x over previous
//
#include <hip/hip_runtime.h>

constexpr int   FEAT   = 128;
constexpr int   BATCH  = 512;
constexpr int   NNEG   = 4096;
constexpr long  NDATA  = 1200000;
constexpr int   CHUNKS = 8;                       // k-chunks per row in negsim
constexpr float INV_TEMP = 14.285714285714286f;   // 1/0.07 (max possible logit)
constexpr float LOG2E    = 1.4426950408889634f;
constexpr float LN2      = 0.6931471805599453f;
constexpr float K1       = INV_TEMP * LOG2E;      // logit->exp2 scale

typedef float f4 __attribute__((ext_vector_type(4)));

// ---------------- prep: normalize s,t and compute pos logit ----------------
__global__ __launch_bounds__(128) void prep_kernel(
    const float* __restrict__ sf, const float* __restrict__ tf,
    float* __restrict__ s_n, float* __restrict__ t_n, float* __restrict__ pos) {
  const int b = blockIdx.x, t = threadIdx.x;
  const float sv = sf[b * FEAT + t];
  const float tv = tf[b * FEAT + t];
  float ss = sv * sv, tt = tv * tv, st = sv * tv;
#pragma unroll
  for (int m = 1; m < 64; m <<= 1) {
    ss += __shfl_xor(ss, m);
    tt += __shfl_xor(tt, m);
    st += __shfl_xor(st, m);
  }
  __shared__ float sh[6];
  if ((t & 63) == 0) {
    const int w = t >> 6;
    sh[w * 3 + 0] = ss; sh[w * 3 + 1] = tt; sh[w * 3 + 2] = st;
  }
  __syncthreads();
  ss = sh[0] + sh[3]; tt = sh[1] + sh[4]; st = sh[2] + sh[5];
  const float snorm = fmaxf(sqrtf(ss), 1e-12f);
  const float tnorm = fmaxf(sqrtf(tt), 1e-12f);
  s_n[b * FEAT + t] = sv / snorm;
  t_n[b * FEAT + t] = tv / tnorm;
  if (t == 0) pos[b] = st / (snorm * tnorm) * INV_TEMP;
}

// ------------- negsim: gathered dots + partial sum of exp(logit-C) ---------
// 8 k's in flight per iteration: 8 independent gather loads + 8 independent
// shuffle-reduce chains to hide HBM gather latency.
__global__ __launch_bounds__(256) void negsim_kernel(
    const float* __restrict__ neg, const int* __restrict__ nidx,
    const float* __restrict__ s_n, float* __restrict__ sumexp) {
  const int blk   = blockIdx.x;
  const int b     = blk >> 3;          // row
  const int chunk = blk & (CHUNKS - 1);
  const int lane  = threadIdx.x & 63;
  const int w     = threadIdx.x >> 6;  // wave id (0..3)
  const float2 s2 = *(const float2*)(s_n + b * FEAT + 2 * lane);
  constexpr int KPC = NNEG / CHUNKS;   // 512 k per chunk
  constexpr int KPW = KPC / 4;         // 128 k per wave
  const int* row_idx = nidx + b * NNEG + chunk * KPC + w * KPW;
  float acc = 0.f;
  for (int k = 0; k < KPW; k += 8) {
    int   idx[8];
    float p[8];
#pragma unroll
    for (int u = 0; u < 8; ++u) idx[u] = row_idx[k + u];   // wave-uniform s_loads
    float2 nv[8];
#pragma unroll
    for (int u = 0; u < 8; ++u)
      nv[u] = *(const float2*)(neg + (long)idx[u] * FEAT + 2 * lane);
#pragma unroll
    for (int u = 0; u < 8; ++u) p[u] = fmaf(s2.x, nv[u].x, s2.y * nv[u].y);
#pragma unroll
    for (int m = 1; m < 64; m <<= 1) {
#pragma unroll
      for (int u = 0; u < 8; ++u) p[u] += __shfl_xor(p[u], m);
    }
    // exp(logit - C) = exp2(cos*K1 - K1), cos <= 1 so arg <= 0 (no overflow)
#pragma unroll
    for (int u = 0; u < 8; ++u) acc += exp2f(fmaf(p[u], K1, -K1));
  }
  __shared__ float part[4];
  if (lane == 0) part[w] = acc;
  __syncthreads();
  if (threadIdx.x == 0)
    sumexp[b * CHUNKS + chunk] = part[0] + part[1] + part[2] + part[3];
}

// --------------- loss: logsumexp per row, mean over rows -------------------
__global__ __launch_bounds__(512) void loss_kernel(
    const float* __restrict__ pos, const float* __restrict__ sumexp,
    float* __restrict__ out) {
  const int t = threadIdx.x;
  const float p = pos[t];
  float tot = exp2f(fmaf(p, LOG2E, -K1));  // exp(p - C)
#pragma unroll
  for (int c = 0; c < CHUNKS; ++c) tot += sumexp[t * CHUNKS + c];
  float l = INV_TEMP + log2f(tot) * LN2 - p;  // C + ln(tot) - p
#pragma unroll
  for (int m = 1; m < 64; m <<= 1) l += __shfl_xor(l, m);
  __shared__ float sh[8];
  if ((t & 63) == 0) sh[t >> 6] = l;
  __syncthreads();
  if (t == 0) {
    float s = 0.f;
#pragma unroll
    for (int i = 0; i < 8; ++i) s += sh[i];
    out[0] = s / (float)BATCH;
  }
}

// --------------------- copy bank -> output ---------------------------------
// f4 (native vector) nontemporal loads; dst is only 4B-aligned (out+1) so
// stores are scalar dwords -- a wave's 4 store instrs still cover a
// contiguous 1KB region, so L2 write-combines full lines.
__global__ __launch_bounds__(256) void copy_kernel(
    const float* __restrict__ src, float* __restrict__ dst, long n4) {
  long i = (long)blockIdx.x * blockDim.x + threadIdx.x;
  const long stride = (long)gridDim.x * blockDim.x;
  for (; i < n4; i += stride) {
    const f4 v = __builtin_nontemporal_load((const f4*)src + i);
    float* d = dst + 4 * i;
    __builtin_nontemporal_store(v.x, d + 0);
    __builtin_nontemporal_store(v.y, d + 1);
    __builtin_nontemporal_store(v.z, d + 2);
    __builtin_nontemporal_store(v.w, d + 3);
  }
}

// ------------- EMA scatter update with last-writer-wins --------------------
__global__ __launch_bounds__(128) void update_kernel(
    const float* __restrict__ neg, const float* __restrict__ t_n,
    const int* __restrict__ indices, float* __restrict__ dst) {
  const int b = blockIdx.x, t = threadIdx.x;
  __shared__ int sidx[BATCH];
  __shared__ int flag;
  if (t == 0) flag = 0;
  for (int j = t; j < BATCH; j += 128) sidx[j] = indices[j];
  __syncthreads();
  const int idx = sidx[b];
  int later = 0;
  for (int j = t; j < BATCH; j += 128)
    if (j > b && sidx[j] == idx) later = 1;
  if (later) flag = 1;  // benign same-value race
  __syncthreads();
  if (flag) return;     // a later batch element writes this row (last wins)
  const float u = 0.5f * neg[(long)idx * FEAT + t] + 0.5f * t_n[b * FEAT + t];
  float uu = u * u;
#pragma unroll
  for (int m = 1; m < 64; m <<= 1) uu += __shfl_xor(uu, m);
  __shared__ float sh2[2];
  if ((t & 63) == 0) sh2[t >> 6] = uu;
  __syncthreads();
  const float nrm = fmaxf(sqrtf(sh2[0] + sh2[1]), 1e-12f);
  dst[(long)idx * FEAT + t] = u / nrm;
}

extern "C" void kernel_launch(void* const* d_in, const int* in_sizes, int n_in,
                              void* d_out, int out_size, void* d_ws, size_t ws_size,
                              hipStream_t stream) {
  const float* student   = (const float*)d_in[0];
  const float* teacher   = (const float*)d_in[1];
  const float* negatives = (const float*)d_in[2];
  const int*   indices   = (const int*)d_in[3];
  const int*   neg_idx   = (const int*)d_in[4];
  float* out = (float*)d_out;

  float* ws     = (float*)d_ws;
  float* s_n    = ws;                        // [512*128]
  float* t_n    = s_n + BATCH * FEAT;        // [512*128]
  float* pos    = t_n + BATCH * FEAT;        // [512]
  float* sumexp = pos + BATCH;               // [512*CHUNKS]

  prep_kernel<<<BATCH, 128, 0, stream>>>(student, teacher, s_n, t_n, pos);
  negsim_kernel<<<BATCH * CHUNKS, 256, 0, stream>>>(negatives, neg_idx, s_n, sumexp);
  loss_kernel<<<1, 512, 0, stream>>>(pos, sumexp, out);
  copy_kernel<<<2048, 256, 0, stream>>>(negatives, out + 1, NDATA * (long)FEAT / 4);
  update_kernel<<<BATCH, 128, 0, stream>>>(negatives, t_n, indices, out + 1);
}

// Round 5
// 397.544 us; speedup vs baseline: 2.2599x; 1.0115x over previous
//
#include <hip/hip_runtime.h>

constexpr int   FEAT   = 128;
constexpr int   BATCH  = 512;
constexpr int   NNEG   = 4096;
constexpr long  NDATA  = 1200000;
constexpr int   CHUNKS = 8;                       // k-chunks per row in negsim
constexpr int   NCOPY  = 1024;                    // persistent copy blocks
constexpr float INV_TEMP = 14.285714285714286f;   // 1/0.07 (max possible logit)
constexpr float LOG2E    = 1.4426950408889634f;
constexpr float LN2      = 0.6931471805599453f;
constexpr float K1       = INV_TEMP * LOG2E;      // logit->exp2 scale

typedef float f4 __attribute__((ext_vector_type(4)));

// ---------------- prep: normalize s,t and compute pos logit ----------------
__global__ __launch_bounds__(128) void prep_kernel(
    const float* __restrict__ sf, const float* __restrict__ tf,
    float* __restrict__ s_n, float* __restrict__ t_n, float* __restrict__ pos) {
  const int b = blockIdx.x, t = threadIdx.x;
  const float sv = sf[b * FEAT + t];
  const float tv = tf[b * FEAT + t];
  float ss = sv * sv, tt = tv * tv, st = sv * tv;
#pragma unroll
  for (int m = 1; m < 64; m <<= 1) {
    ss += __shfl_xor(ss, m);
    tt += __shfl_xor(tt, m);
    st += __shfl_xor(st, m);
  }
  __shared__ float sh[6];
  if ((t & 63) == 0) {
    const int w = t >> 6;
    sh[w * 3 + 0] = ss; sh[w * 3 + 1] = tt; sh[w * 3 + 2] = st;
  }
  __syncthreads();
  ss = sh[0] + sh[3]; tt = sh[1] + sh[4]; st = sh[2] + sh[5];
  const float snorm = fmaxf(sqrtf(ss), 1e-12f);
  const float tnorm = fmaxf(sqrtf(tt), 1e-12f);
  s_n[b * FEAT + t] = sv / snorm;
  t_n[b * FEAT + t] = tv / tnorm;
  if (t == 0) pos[b] = st / (snorm * tnorm) * INV_TEMP;
}

// ------ work: copy (blocks < NCOPY, persistent) + negsim (the rest) --------
// Copy blocks stream the bank with CACHED loads (warming L2/L3 for the
// gather, same array) and nontemporal stores (dst never re-read).
// Negsim blocks: 8 k's in flight -- 8 independent gather loads + 8
// independent shuffle-reduce chains to hide HBM gather latency.
__global__ __launch_bounds__(256) void work_kernel(
    const float* __restrict__ neg, const int* __restrict__ nidx,
    const float* __restrict__ s_n, float* __restrict__ sumexp,
    float* __restrict__ dst) {
  __shared__ float part[4];
  if (blockIdx.x < NCOPY) {
    const long n4 = NDATA * (long)FEAT / 4;
    long i = (long)blockIdx.x * blockDim.x + threadIdx.x;
    const long stride = (long)NCOPY * blockDim.x;
    for (; i < n4; i += stride) {
      const f4 v = *((const f4*)neg + i);   // cached load: warms L3 for gather
      float* d = dst + 4 * i;
      __builtin_nontemporal_store(v.x, d + 0);
      __builtin_nontemporal_store(v.y, d + 1);
      __builtin_nontemporal_store(v.z, d + 2);
      __builtin_nontemporal_store(v.w, d + 3);
    }
    return;
  }
  const int blk   = blockIdx.x - NCOPY;
  const int b     = blk >> 3;          // row
  const int chunk = blk & (CHUNKS - 1);
  const int lane  = threadIdx.x & 63;
  const int w     = threadIdx.x >> 6;  // wave id (0..3)
  const float2 s2 = *(const float2*)(s_n + b * FEAT + 2 * lane);
  constexpr int KPC = NNEG / CHUNKS;   // 512 k per chunk
  constexpr int KPW = KPC / 4;         // 128 k per wave
  const int* row_idx = nidx + b * NNEG + chunk * KPC + w * KPW;
  float acc = 0.f;
  for (int k = 0; k < KPW; k += 8) {
    int   idx[8];
    float p[8];
#pragma unroll
    for (int u = 0; u < 8; ++u) idx[u] = row_idx[k + u];
    float2 nv[8];
#pragma unroll
    for (int u = 0; u < 8; ++u)
      nv[u] = *(const float2*)(neg + (long)idx[u] * FEAT + 2 * lane);
#pragma unroll
    for (int u = 0; u < 8; ++u) p[u] = fmaf(s2.x, nv[u].x, s2.y * nv[u].y);
#pragma unroll
    for (int m = 1; m < 64; m <<= 1) {
#pragma unroll
      for (int u = 0; u < 8; ++u) p[u] += __shfl_xor(p[u], m);
    }
    // exp(logit - C) = exp2(cos*K1 - K1), cos <= 1 so arg <= 0 (no overflow)
#pragma unroll
    for (int u = 0; u < 8; ++u) acc += exp2f(fmaf(p[u], K1, -K1));
  }
  if (lane == 0) part[w] = acc;
  __syncthreads();
  if (threadIdx.x == 0)
    sumexp[b * CHUNKS + chunk] = part[0] + part[1] + part[2] + part[3];
}

// ------ finish: block 0 = loss (logsumexp mean); blocks 1..512 = EMA -------
__global__ __launch_bounds__(256) void finish_kernel(
    const float* __restrict__ pos, const float* __restrict__ sumexp,
    const float* __restrict__ neg, const float* __restrict__ t_n,
    const int* __restrict__ indices, float* __restrict__ out) {
  const int t = threadIdx.x;
  if (blockIdx.x == 0) {
    float lsum = 0.f;
#pragma unroll
    for (int r = t; r < BATCH; r += 256) {
      const float p = pos[r];
      float tot = exp2f(fmaf(p, LOG2E, -K1));  // exp(p - C)
#pragma unroll
      for (int c = 0; c < CHUNKS; ++c) tot += sumexp[r * CHUNKS + c];
      lsum += INV_TEMP + log2f(tot) * LN2 - p; // C + ln(tot) - p
    }
#pragma unroll
    for (int m = 1; m < 64; m <<= 1) lsum += __shfl_xor(lsum, m);
    __shared__ float sh[4];
    if ((t & 63) == 0) sh[t >> 6] = lsum;
    __syncthreads();
    if (t == 0) out[0] = (sh[0] + sh[1] + sh[2] + sh[3]) / (float)BATCH;
    return;
  }
  // ---- EMA update with last-writer-wins, row b ----
  const int b = blockIdx.x - 1;
  float* dst = out + 1;
  __shared__ int sidx[BATCH];
  __shared__ int flag;
  if (t == 0) flag = 0;
  for (int j = t; j < BATCH; j += 256) sidx[j] = indices[j];
  __syncthreads();
  const int idx = sidx[b];
  int later = 0;
  for (int j = t; j < BATCH; j += 256)
    if (j > b && sidx[j] == idx) later = 1;
  if (later) flag = 1;  // benign same-value race
  __syncthreads();
  if (flag) return;     // a later batch element writes this row (last wins)
  float u = 0.f, uu = 0.f;
  if (t < FEAT) {
    u = 0.5f * neg[(long)idx * FEAT + t] + 0.5f * t_n[b * FEAT + t];
    uu = u * u;
  }
#pragma unroll
  for (int m = 1; m < 64; m <<= 1) uu += __shfl_xor(uu, m);
  __shared__ float sh2[2];
  if (t == 0 || t == 64) sh2[t >> 6] = uu;
  __syncthreads();
  if (t < FEAT) {
    const float nrm = fmaxf(sqrtf(sh2[0] + sh2[1]), 1e-12f);
    dst[(long)idx * FEAT + t] = u / nrm;
  }
}

extern "C" void kernel_launch(void* const* d_in, const int* in_sizes, int n_in,
                              void* d_out, int out_size, void* d_ws, size_t ws_size,
                              hipStream_t stream) {
  const float* student   = (const float*)d_in[0];
  const float* teacher   = (const float*)d_in[1];
  const float* negatives = (const float*)d_in[2];
  const int*   indices   = (const int*)d_in[3];
  const int*   neg_idx   = (const int*)d_in[4];
  float* out = (float*)d_out;

  float* ws     = (float*)d_ws;
  float* s_n    = ws;                        // [512*128]
  float* t_n    = s_n + BATCH * FEAT;        // [512*128]
  float* pos    = t_n + BATCH * FEAT;        // [512]
  float* sumexp = pos + BATCH;               // [512*CHUNKS]

  prep_kernel<<<BATCH, 128, 0, stream>>>(student, teacher, s_n, t_n, pos);
  work_kernel<<<NCOPY + BATCH * CHUNKS, 256, 0, stream>>>(
      negatives, neg_idx, s_n, sumexp, out + 1);
  finish_kernel<<<1 + BATCH, 256, 0, stream>>>(
      pos, sumexp, negatives, t_n, indices, out);
}